// Round 5
// baseline (102.760 us; speedup 1.0000x reference)
//
#include <hip/hip_runtime.h>
#include <math.h>
#include <stdint.h>

typedef __attribute__((ext_vector_type(8))) short short8;
typedef __attribute__((ext_vector_type(4))) float f32x4;

#define B_  16
#define C_  256
#define HW_ 4096
#define KK_ 49
#define CR_ 64

__device__ __forceinline__ ushort f2bf(float f) {
    union { float f; uint32_t u; } v; v.f = f;
    uint32_t r = (v.u + 0x7FFFu + ((v.u >> 16) & 1u)) >> 16;
    return (ushort)r;
}

// ---------------- K1: global average pool ----------------
__global__ __launch_bounds__(256) void pool_kernel(const float* __restrict__ x,
                                                   float* __restrict__ pooled) {
    int bc = blockIdx.x;
    const float4* p4 = (const float4*)(x + (size_t)bc * HW_);
    float s = 0.f;
    for (int i = threadIdx.x; i < HW_ / 4; i += 256) {
        float4 v = p4[i];
        s += (v.x + v.y) + (v.z + v.w);
    }
#pragma unroll
    for (int off = 32; off > 0; off >>= 1) s += __shfl_down(s, off);
    __shared__ float red[4];
    if ((threadIdx.x & 63) == 0) red[threadIdx.x >> 6] = s;
    __syncthreads();
    if (threadIdx.x == 0)
        pooled[bc] = (red[0] + red[1] + red[2] + red[3]) * (1.f / HW_);
}

// ---------------- K2: h = gelu(pooled @ w1^T + b1) ----------------
__global__ __launch_bounds__(64) void mlp_kernel(const float* __restrict__ pooled,
                                                 const float* __restrict__ w1,
                                                 const float* __restrict__ b1,
                                                 float* __restrict__ h) {
    int b = blockIdx.x;
    int r = threadIdx.x;
    __shared__ float pr[C_];
    for (int i = r; i < C_; i += 64) pr[i] = pooled[b * C_ + i];
    __syncthreads();
    float acc = b1[r];
    const float* wr = w1 + (size_t)r * C_;
    for (int c = 0; c < C_; c += 4) {
        float4 wv = *(const float4*)(wr + c);
        acc += pr[c] * wv.x + pr[c + 1] * wv.y + pr[c + 2] * wv.z + pr[c + 3] * wv.w;
    }
    h[b * CR_ + r] = 0.5f * acc * (1.f + erff(acc * 0.70710678118654752f));
}

// ---------------- K3: fused[b,m] = dw[m] + b2[m] + h[b,:] @ w2[m,:] ----------------
__global__ __launch_bounds__(256) void genw_kernel(const float* __restrict__ h,
                                                   const float* __restrict__ w2,
                                                   const float* __restrict__ b2,
                                                   const float* __restrict__ dw,
                                                   float* __restrict__ fused) {
    __shared__ float hs[B_ * CR_];
    int m = blockIdx.x * 256 + threadIdx.x;
    for (int i = threadIdx.x; i < B_ * CR_; i += 256) hs[i] = h[i];
    float wrow[CR_];
    const float4* w4 = (const float4*)(w2 + (size_t)m * CR_);
#pragma unroll
    for (int i = 0; i < CR_ / 4; i++) {
        float4 v = w4[i];
        wrow[4 * i] = v.x; wrow[4 * i + 1] = v.y;
        wrow[4 * i + 2] = v.z; wrow[4 * i + 3] = v.w;
    }
    float base = b2[m] + dw[m];
    __syncthreads();
    for (int b = 0; b < B_; b++) {
        float acc = base;
        const float* hb = hs + b * CR_;
#pragma unroll
        for (int r = 0; r < CR_; r++) acc += hb[r] * wrow[r];
        fused[(size_t)b * (C_ * KK_) + m] = acc;
    }
}

// ---------------- K4: pack pw_weight fp32 [o][c] -> Pa bf16 [o/16][c/8][16][8] ----------------
__global__ __launch_bounds__(256) void prep_kernel(const float* __restrict__ pw,
                                                   ushort* __restrict__ Pa) {
    int idx = blockIdx.x * 256 + threadIdx.x;   // 65536
    int o = idx >> 8, c = idx & 255;
    Pa[(size_t)(((o >> 4) * 32) + (c >> 3)) * 128 + (o & 15) * 8 + (c & 7)] = f2bf(pw[idx]);
}

// ---------------- K5: depthwise 7x7, 4x4 micro-tile per thread ----------------
// Block: 8 ch x 16 rows. Wave = channel (wk broadcast from SGPRs).
// Thread: cg=lane&15 (4 cols), rg=lane>>4 (4 rows). 30 vector LDS reads/thread.
// Ug layout: [b][p>>4][cb][p&15][c&7] bf16  (unchanged; pw reads as before)
__global__ __launch_bounds__(512, 4) void dw_kernel(const float* __restrict__ x,
                                                    const float* __restrict__ fused,
                                                    ushort* __restrict__ Ug) {
    __shared__ __align__(16) float xs[8 * 22 * 72];   // 50688 B; Us (16 KB) aliases later
    ushort* Us = (ushort*)xs;

    const int strip = blockIdx.x;            // 0..3
    const int cb    = blockIdx.y;            // 0..31
    const int b     = blockIdx.z;
    const int tid   = threadIdx.x;           // 0..511
    const int wid   = tid >> 6;              // channel within group (wave-uniform)
    const int lane  = tid & 63;
    const int c0    = cb * 8;
    const int r0    = strip * 16;

    // ---- stage x: wave wid loads channel wid; rows r0-3 .. r0+18 ----
    {
        const float* xp = x + (((size_t)(b * C_ + c0 + wid)) << 12);
        float* xd = xs + wid * 1584;
#pragma unroll
        for (int row = 0; row < 22; row++) {
            int gr = r0 + row - 3;           // wave-uniform -> scalar branch
            float v = 0.f;
            if ((unsigned)gr < 64u) v = xp[(gr << 6) + lane];
            xd[row * 72 + 3 + lane] = v;
        }
        // edge columns 0..2 and 67..71 always zero (22 rows x 8 cols)
        for (int j = lane; j < 176; j += 64) {
            int row = j >> 3, e = j & 7;
            int col = (e < 3) ? e : (64 + e);
            xd[row * 72 + col] = 0.f;
        }
    }

    // ---- weights -> SGPRs: one load + 49 readlanes, PINNED against remat ----
    float wk[49];
    {
        const float* fp = fused + (((size_t)b * C_) + c0 + wid) * KK_;
        float v = (lane < KK_) ? fp[lane] : 0.f;
        int vi = __float_as_int(v);
#pragma unroll
        for (int t = 0; t < 49; t++) {
            wk[t] = __int_as_float(__builtin_amdgcn_readlane(vi, t));
            asm volatile("" : "+s"(wk[t]));   // pin in SGPR; forbid remat
        }
    }
    __syncthreads();

    const int cg = lane & 15;   // 4-col group
    const int rg = lane >> 4;   // 4-row group
    float acc[4][4];
#pragma unroll
    for (int ro = 0; ro < 4; ro++)
#pragma unroll
        for (int co = 0; co < 4; co++) acc[ro][co] = 0.f;

    const float* xbase = xs + wid * 1584 + (rg * 4) * 72 + cg * 4;
#pragma unroll
    for (int rr = 0; rr < 10; rr++) {
        float xr[10];
        *(float4*)&xr[0] = *(const float4*)(xbase + rr * 72);       // 16B aligned
        *(float4*)&xr[4] = *(const float4*)(xbase + rr * 72 + 4);
        *(float2*)&xr[8] = *(const float2*)(xbase + rr * 72 + 8);
        const int olo = (rr - 6 < 0) ? 0 : rr - 6;
        const int ohi = (rr < 3) ? rr : 3;
#pragma unroll
        for (int ro = olo; ro <= ohi; ro++) {
            const int ki = rr - ro;
#pragma unroll
            for (int j = 0; j < 7; j++) {
#pragma unroll
                for (int co = 0; co < 4; co++)
                    acc[ro][co] = fmaf(xr[co + j], wk[ki * 7 + j], acc[ro][co]);
            }
        }
    }
    __syncthreads();   // all xs reads done; safe to alias with Us

    // ---- stage bf16 outputs (chunk-XOR swizzle keeps scatter <=8-way) ----
#pragma unroll
    for (int ro = 0; ro < 4; ro++) {
#pragma unroll
        for (int co = 0; co < 4; co++) {
            int o = rg * 4 + ro;            // 0..15
            int c = cg * 4 + co;            // 0..63
            int q = o * 4 + (c >> 4);       // 0..63
            int part = (c & 15) ^ (q & 15);
            Us[q * 128 + part * 8 + wid] = f2bf(acc[ro][co]);
        }
    }
    __syncthreads();

    // ---- coalesced writeout: 64 chunks x 256B ----
    for (int t = tid; t < 1024; t += 512) {
        int q = t >> 4, part = t & 15;
        int o = q >> 2, cgrp = q & 3;
        size_t e = ((((size_t)b * 256) + (size_t)((r0 + o) * 4 + cgrp)) * 32 + cb) * 128
                   + (size_t)part * 8;
        *(uint4*)(Ug + e) = *(const uint4*)(Us + q * 128 + ((part ^ (q & 15)) * 8));
    }
}

// ---------------- K6: pointwise GEMM, bf16 MFMA, BK=32 ping-pong pipeline ----------------
#define GLDS16(gp, lp) __builtin_amdgcn_global_load_lds(\
    (const __attribute__((address_space(1))) uint32_t*)(gp), \
    (__attribute__((address_space(3))) uint32_t*)(lp), 16, 0, 0)

__global__ __launch_bounds__(256, 2) void pw_kernel(const ushort* __restrict__ Pa,
                                                    const ushort* __restrict__ Ug,
                                                    float* __restrict__ Y) {
    __shared__ ushort As[2][8192];   // per buf: 256o x 32k  [obl(16)][kb(4)][16][8]
    __shared__ ushort Bs[2][4096];   // per buf: 128p x 32k  [pgl(8)][kb(4)][16][8]
    const int pb   = blockIdx.x;     // 0..31
    const int b    = blockIdx.y;
    const int tid  = threadIdx.x;
    const int w    = tid >> 6;
    const int lane = tid & 63;
    const int oi   = lane & 15;
    const int kq   = lane >> 4;      // 0..3

    f32x4 acc[4][8];
#pragma unroll
    for (int mi = 0; mi < 4; mi++)
#pragma unroll
        for (int ni = 0; ni < 8; ni++)
            acc[mi][ni] = (f32x4){0.f, 0.f, 0.f, 0.f};

    const size_t ubase = (((size_t)b * 256) + (size_t)pb * 8) * 32 * 128;

#define STAGE(BUF, KB0)                                                          \
    for (int q = w; q < 24; q += 4) {                                            \
        const ushort* src; ushort* dst;                                          \
        if (q < 16) { src = Pa + ((size_t)q * 32 + (KB0)) * 128;                 \
                      dst = &As[BUF][q * 512]; }                                 \
        else { int pg = q - 16;                                                  \
               src = Ug + ubase + ((size_t)pg * 32 + (KB0)) * 128;               \
               dst = &Bs[BUF][pg * 512]; }                                       \
        GLDS16(src + lane * 8, dst);                                             \
    }

    STAGE(0, 0)

#pragma unroll
    for (int ki = 0; ki < 8; ki++) {
        const int buf = ki & 1;
        if (ki < 7) {
            STAGE(buf ^ 1, (ki + 1) * 4)
            asm volatile("s_waitcnt vmcnt(6)" ::: "memory");
        } else {
            asm volatile("s_waitcnt vmcnt(0)" ::: "memory");
        }
        __builtin_amdgcn_s_barrier();
        __builtin_amdgcn_sched_barrier(0);

        short8 af[4], bf[8];
#pragma unroll
        for (int mi = 0; mi < 4; mi++)
            af[mi] = *(const short8*)&As[buf][(w * 4 + mi) * 512 + kq * 128 + oi * 8];
#pragma unroll
        for (int ni = 0; ni < 8; ni++)
            bf[ni] = *(const short8*)&Bs[buf][ni * 512 + kq * 128 + oi * 8];
#pragma unroll
        for (int mi = 0; mi < 4; mi++)
#pragma unroll
            for (int ni = 0; ni < 8; ni++)
                acc[mi][ni] = __builtin_amdgcn_mfma_f32_16x16x32_bf16(
                    af[mi], bf[ni], acc[mi][ni], 0, 0, 0);

        __builtin_amdgcn_s_barrier();
        __builtin_amdgcn_sched_barrier(0);
    }

    float* yb = Y + ((size_t)b << 20);
    const int p0 = pb * 128;
#pragma unroll
    for (int mi = 0; mi < 4; mi++) {
#pragma unroll
        for (int ni = 0; ni < 8; ni++) {
            int p = p0 + ni * 16 + oi;
#pragma unroll
            for (int r = 0; r < 4; r++) {
                int o = w * 64 + mi * 16 + kq * 4 + r;
                yb[(size_t)o * HW_ + p] = acc[mi][ni][r];
            }
        }
    }
#undef STAGE
}

extern "C" void kernel_launch(void* const* d_in, const int* in_sizes, int n_in,
                              void* d_out, int out_size, void* d_ws, size_t ws_size,
                              hipStream_t stream) {
    const float* x  = (const float*)d_in[0];
    const float* dw = (const float*)d_in[1];
    const float* pw = (const float*)d_in[2];
    const float* w1 = (const float*)d_in[3];
    const float* b1 = (const float*)d_in[4];
    const float* w2 = (const float*)d_in[5];
    const float* b2 = (const float*)d_in[6];
    float* out = (float*)d_out;

    char* ws = (char*)d_ws;
    float*  pooled = (float*)(ws);                    // 16384 B
    float*  h      = (float*)(ws + 16384);            // 4096 B
    float*  fused  = (float*)(ws + 20480);            // 802816 B
    ushort* Pa     = (ushort*)(ws + 823296);          // 131072 B
    ushort* Ug     = (ushort*)(ws + 1048576);         // 33554432 B

    hipLaunchKernelGGL(pool_kernel, dim3(B_ * C_), dim3(256), 0, stream, x, pooled);
    hipLaunchKernelGGL(mlp_kernel,  dim3(B_), dim3(64), 0, stream, pooled, w1, b1, h);
    hipLaunchKernelGGL(genw_kernel, dim3(49), dim3(256), 0, stream, h, w2, b2, dw, fused);
    hipLaunchKernelGGL(prep_kernel, dim3(256), dim3(256), 0, stream, pw, Pa);
    hipLaunchKernelGGL(dw_kernel,   dim3(4, 32, B_), dim3(512), 0, stream, x, fused, Ug);
    hipLaunchKernelGGL(pw_kernel,   dim3(32, B_), dim3(256), 0, stream, Pa, Ug, out);
}